// Round 1
// 66.519 us; speedup vs baseline: 1.0519x; 1.0519x over previous
//
#include <hip/hip_runtime.h>
#include <stdint.h>

// Maj3FC: out[b,c] = 2.25 * sum_g sign( sum_{k<3} sign(x[b,3g+k])*sign(w[c,3g+k]) )
// B=512, C_IN=1536, C_OUT=512, G=512 groups of 3. Exact integer math -> absmax 0.
//
// R7: bit-plane repack. R6's 3-bit-field maj3w cost ~2.7 VALU ops/group
// (per-field popcount extraction dominates). New format: 6 sign bit-planes
// (P0,P1,P2,N0,N1,N2), 32 groups/word. Per 32 groups: pos/neg masks (12 ops
// w/ v_and_or), 2-bit carry-save cp/cn (8), 2-bit compare gt/ge (9), 2 fused
// v_bcnt = ~31 ops -> ~1.0 op/group, 2.8x VALU cut. DS: 24 b128/thread (was
// 26). Same 16x8 tile, split-K 2, 2048 blocks, 32 waves/CU, VGPR<=64 target.
// Pack: 64 blocks, all 256 threads active (1 slice = 96 floats each), direct
// global reads -> kills R6's 1024-block latency tail.
//
// Row layout (96 dwords = 24 uint4): 8 chunks of 64 groups. Chunk = 3 uint4:
//   u4[0] = (P0a,P0b,P1a,P1b)  u4[1] = (P2a,P2b,N0a,N0b)  u4[2] = (N1a,N1b,N2a,N2b)
// where a = groups [0,32), b = [32,64) of the chunk, Pk/Nk = sign planes of
// element k within the group.

#define CIN     1536
#define B_DIM   512
#define COUT    512
#define GROUPS  512   // CIN/3, exact -> no pad correction
#define ROW_U4  24    // uint4 per packed row
#define XSTRIDE 25    // LDS row stride in uint4 (100 dwords; 100%32=4 -> conflict-free)

// ---------------- pack kernel ----------------
// 64 blocks x 256 threads. thread t -> (row = t>>4, slice = t&15); packs
// 96 consecutive floats (32 groups) into 6 plane words.
__global__ __launch_bounds__(256) void pack_kernel(
    const float* __restrict__ x, const float* __restrict__ w,
    uint32_t* __restrict__ packed) {
  const int t = blockIdx.x * 256 + threadIdx.x;  // 0..16383
  const int row = t >> 4;
  const int slice = t & 15;
  const float* src = (row < B_DIM) ? (x + (size_t)row * CIN)
                                   : (w + (size_t)(row - B_DIM) * CIN);
  const float4* s4 = (const float4*)(src + slice * 96);

  unsigned P0 = 0, P1 = 0, P2 = 0, N0 = 0, N1 = 0, N2 = 0;
  #pragma unroll
  for (int i = 0; i < 8; i++) {
    float4 q0 = s4[3 * i], q1 = s4[3 * i + 1], q2 = s4[3 * i + 2];
    float f[12] = {q0.x, q0.y, q0.z, q0.w, q1.x, q1.y, q1.z, q1.w,
                   q2.x, q2.y, q2.z, q2.w};
    #pragma unroll
    for (int g = 0; g < 4; g++) {
      const int bit = i * 4 + g;
      float a = f[3 * g], b = f[3 * g + 1], c = f[3 * g + 2];
      P0 |= (a > 0.0f ? 1u : 0u) << bit;
      N0 |= (a < 0.0f ? 1u : 0u) << bit;
      P1 |= (b > 0.0f ? 1u : 0u) << bit;
      N1 |= (b < 0.0f ? 1u : 0u) << bit;
      P2 |= (c > 0.0f ? 1u : 0u) << bit;
      N2 |= (c < 0.0f ? 1u : 0u) << bit;
    }
  }
  // chunk = slice>>1, a/b half = slice&1
  uint32_t* dst = packed + (size_t)row * 96 + (slice >> 1) * 12 + (slice & 1);
  dst[0] = P0;  dst[2] = P1;  dst[4]  = P2;
  dst[6] = N0;  dst[8] = N1;  dst[10] = N2;
}

// ---------------- main kernel ----------------
// 32 groups at once. Per group: cp = #(+1 products), cn = #(-1 products),
// contribution to acc = (cp>cn) + (cp>=cn) = sign(cp-cn)+1.
// sum(sign) over 512 groups = acc_total - 512.
__device__ __forceinline__ void maj32(
    unsigned xp0, unsigned xp1, unsigned xp2,
    unsigned xn0, unsigned xn1, unsigned xn2,
    unsigned wp0, unsigned wp1, unsigned wp2,
    unsigned wn0, unsigned wn1, unsigned wn2,
    int& acc) {
  // product sign masks per element-plane
  unsigned pos0 = (xp0 & wp0) | (xn0 & wn0);
  unsigned pos1 = (xp1 & wp1) | (xn1 & wn1);
  unsigned pos2 = (xp2 & wp2) | (xn2 & wn2);
  unsigned neg0 = (xp0 & wn0) | (xn0 & wp0);
  unsigned neg1 = (xp1 & wn1) | (xn1 & wp1);
  unsigned neg2 = (xp2 & wn2) | (xn2 & wp2);
  // 2-bit carry-save sums: cp = pos0+pos1+pos2 in [0,3], cn likewise
  unsigned sa  = pos0 ^ pos1;
  unsigned cp0 = sa ^ pos2;
  unsigned cp1 = (pos0 & pos1) | (pos2 & sa);
  unsigned sb  = neg0 ^ neg1;
  unsigned cn0 = sb ^ neg2;
  unsigned cn1 = (neg0 & neg1) | (neg2 & sb);
  // 2-bit compare: gt = cp>cn, ge = cp>=cn (per group bit)
  unsigned nh = ~cn1;
  unsigned nl = ~cn0;
  unsigned hi = cp1 & nh;
  unsigned eq = ~(cp1 ^ cn1);
  unsigned gt = hi | (eq & (cp0 & nl));
  unsigned ge = hi | (eq & (cp0 | nl));
  acc += __popc(gt) + __popc(ge);
}

// 16(b) x 8(c) tile, 256 threads, 128 outputs, split-K by 2.
// grid = (64, 32) = 2048 blocks -> 8 blocks/CU -> 32 waves/CU.
// LDS = (16+8)*25*16 + 128*4 = 10.1 KB.
__global__ __launch_bounds__(256, 8) void maj3_kernel(
    const uint4* __restrict__ px, const uint4* __restrict__ pw,
    float* __restrict__ out) {
  __shared__ __align__(16) uint4 sx[16][XSTRIDE];
  __shared__ __align__(16) uint4 sw[8][XSTRIDE];
  __shared__ int comb[128];

  const int b0 = blockIdx.y * 16;
  const int c0 = blockIdx.x * 8;
  const int tid = threadIdx.x;

  // packed rows are dense in global (24 uint4/row); scatter to stride-25 LDS
  const uint4* gx = px + (size_t)b0 * ROW_U4;
  const uint4* gw = pw + (size_t)c0 * ROW_U4;
  #pragma unroll
  for (int i = tid; i < 16 * ROW_U4; i += 256) {
    int r = i / ROW_U4, wd = i - r * ROW_U4;
    sx[r][wd] = gx[i];
  }
  if (tid < 8 * ROW_U4) {
    int r = tid / ROW_U4, wd = tid - r * ROW_U4;
    sw[r][wd] = gw[tid];
  }
  __syncthreads();

  const int o  = tid & 127;  // output index within tile
  const int tx = o & 7;      // c within tile
  const int ty = o >> 3;     // b within tile
  const int h  = tid >> 7;   // K-half: chunks [4h, 4h+4)

  const uint4* xr = &sx[ty][h * 12];
  const uint4* wr = &sw[tx][h * 12];

  int acc = 0;
  #pragma unroll
  for (int i = 0; i < 4; i++) {
    uint4 a0 = xr[3 * i], a1 = xr[3 * i + 1], a2 = xr[3 * i + 2];
    uint4 b0v = wr[3 * i], b1 = wr[3 * i + 1], b2 = wr[3 * i + 2];
    // slice a: groups [64i, 64i+32) of this half
    maj32(a0.x, a0.z, a1.x, a1.z, a2.x, a2.z,
          b0v.x, b0v.z, b1.x, b1.z, b2.x, b2.z, acc);
    // slice b: groups [64i+32, 64i+64)
    maj32(a0.y, a0.w, a1.y, a1.w, a2.y, a2.w,
          b0v.y, b0v.w, b1.y, b1.w, b2.y, b2.w, acc);
  }

  if (h == 1) comb[o] = acc;
  __syncthreads();
  if (h == 0) {
    // acc_total = sum over 512 groups of (sign+1); sum(sign) = acc_total - 512
    int total = acc + comb[o];
    out[(size_t)(b0 + ty) * COUT + (c0 + tx)] = 2.25f * (float)(total - GROUPS);
  }
}

extern "C" void kernel_launch(void* const* d_in, const int* in_sizes, int n_in,
                              void* d_out, int out_size, void* d_ws, size_t ws_size,
                              hipStream_t stream) {
  const float* x = (const float*)d_in[0];   // [512, 1536]
  const float* w = (const float*)d_in[1];   // [512, 1536]
  float* out = (float*)d_out;               // [512, 512]

  uint32_t* packed = (uint32_t*)d_ws;       // [1024][96] dwords = 384 KB
  const uint4* px = (const uint4*)packed;                       // rows 0..511 (x)
  const uint4* pw = (const uint4*)(packed + (size_t)B_DIM * 96); // rows 512..1023 (w)

  pack_kernel<<<64, 256, 0, stream>>>(x, w, packed);

  dim3 grid(COUT / 8, B_DIM / 16);
  maj3_kernel<<<grid, 256, 0, stream>>>(px, pw, out);
}